// Round 4
// baseline (429.952 us; speedup 1.0000x reference)
//
#include <hip/hip_runtime.h>
#include <math.h>

#define NCLS 81
#define NANCH 8732
#define NB 64
#define BUCKET_STRIDE 16     // 64 B cacheline spread for int buckets
#define HSTRIDE 257          // bank-decorrelated histogram copy stride (ints)
#define NCONF_BLK 8732       // 64 anchors per block (8732*64 == 64*8732 anchors)
#define NLOC_BLK  2240       // 35 chunks * 64 batch rows

// ---------------- Kernel A: fused conf loss (reg-path, full-MLP) + loc loss ----------------
// conf: one-hot trick -> conf_loss = lse - dot(x,g); pos <=> g[0]==0.
// Row decomposition (all loads UNCONDITIONAL -> compiler batches ~12 loads/thread):
//   h = (4-(anchor&3))&3 head floats, then 19 always-valid float4s at xr+h
//   (h+76 <= 79 for all h), then 5-h tail floats. Per-lane scalar slot
//   s0 = (q<h ? q : 76+q) covers head+tail uniformly; element 80 is loaded by
//   all 4 lanes but accumulated only by q==0. Only vector slot (q=3,j=4) is
//   clamped+predicated. No data-dependent branch touches any load.
__global__ __launch_bounds__(256) void conf_loc_kernel(
    const float* __restrict__ pred_conf,
    const float* __restrict__ gt_conf,
    const float* __restrict__ pred_loc,
    const float* __restrict__ gt_loc,
    float* __restrict__ cl_out,       // [B*N] cl_neg (0 for positives)
    int* __restrict__ pos_buckets,    // [64*BUCKET_STRIDE], pre-zeroed
    float* __restrict__ row_pos,      // [128] per-row positive-loss sums, pre-zeroed
    float* __restrict__ out)          // loc part accumulates out[64+b]
{
    const int tid = threadIdx.x;
    const int lane = tid & 63, wid = tid >> 6;

    if (blockIdx.x >= NCONF_BLK) {
        // ---- loc part: smooth-L1-quirk loss, one atomic per wave ----
        const int bid = blockIdx.x - NCONF_BLK;
        const int b = bid & 63;         // consecutive blocks -> different b (atomic spread)
        const int chunk = bid >> 6;     // 0..34
        const int idx = chunk * 256 + tid;
        float local = 0.f;
        if (idx < NANCH) {
            const float4* p = (const float4*)(pred_loc + (size_t)b * (NANCH * 4));
            const float4* g = (const float4*)(gt_loc + (size_t)b * (NANCH * 4));
            float4 pv = p[idx];
            float4 gv = g[idx];
            float a0 = fabsf(pv.x - gv.x), a1 = fabsf(pv.y - gv.y);
            float a2 = fabsf(pv.z - gv.z), a3 = fabsf(pv.w - gv.w);
            local  = (a0 > 1.f) ? (a0 - 0.5f) : 0.f;
            local += (a1 > 1.f) ? (a1 - 0.5f) : 0.f;
            local += (a2 > 1.f) ? (a2 - 0.5f) : 0.f;
            local += (a3 > 1.f) ? (a3 - 0.5f) : 0.f;
        }
        for (int off = 32; off; off >>= 1) local += __shfl_xor(local, off);
        if (lane == 0 && local != 0.f) atomicAdd(&out[64 + b], local);
        return;
    }

    // ---- conf part ----
    const int a_loc = tid >> 2;                 // anchor within block
    const int q = tid & 3;                      // lane within anchor
    const int anchor = blockIdx.x * 64 + a_loc; // < 558848
    const int h = (4 - (anchor & 3)) & 3;       // (anchor*81 + h) % 4 == 0
    const size_t fbase = (size_t)anchor * NCLS;
    const float* xr = pred_conf + fbase;
    const float* gr = gt_conf + fbase;
    const float4* x4 = (const float4*)(xr + h); // 16B-aligned by construction
    const float4* g4 = (const float4*)(gr + h);

    // ---- issue ALL loads up front (14 independent per thread) ----
    const int s0 = (q < h) ? q : 76 + q;        // unique valid element per lane
    float xs0 = xr[s0];
    float gs0 = gr[s0];
    float xs1 = xr[80];                         // all lanes; only q==0 accumulates
    float gs1 = gr[80];

    float4 xv[5], gv[5];
#pragma unroll
    for (int j = 0; j < 5; ++j) {
        const int k = 4 * j + q;                // 0..19; only k==19 invalid
        const int kc = (k < 19) ? k : 18;       // clamp -> always in-bounds
        xv[j] = x4[kc];
        gv[j] = g4[kc];
    }

    // ---- consume ----
    float se = 0.f, dot = 0.f;
#pragma unroll
    for (int j = 0; j < 5; ++j) {
        const bool valid = (4 * j + q) < 19;
        float4 x = xv[j], g = gv[j];
        float e = __expf(x.x) + __expf(x.y) + __expf(x.z) + __expf(x.w);
        float d = x.x * g.x + x.y * g.y + x.z * g.z + x.w * g.w;
        se  += valid ? e : 0.f;
        dot += valid ? d : 0.f;
    }
    se  += __expf(xs0);
    dot += xs0 * gs0;
    const bool q0 = (q == 0);
    se  += q0 ? __expf(xs1) : 0.f;
    dot += q0 ? xs1 * gs1 : 0.f;

    // class-0 prob for positive detection (meaningful on q==0 lane):
    // h>0 -> scalar slot s0==0; h==0 -> vector slot j=0 (.x = element 0)
    const float g0v = (h > 0) ? gs0 : gv[0].x;

    // reduce across the anchor's 4 lanes
    se  += __shfl_xor(se, 1);  dot += __shfl_xor(dot, 1);
    se  += __shfl_xor(se, 2);  dot += __shfl_xor(dot, 2);
    const float lse = __logf(se);
    const float conf_loss = lse - dot;          // dot == x[label] bit-exact (one-hot)

    bool posf = false;
    if (q0) {
        posf = (g0v == 0.0f);
        cl_out[anchor] = posf ? 0.0f : conf_loss;
    }

    // per-wave reductions: positive-loss row sums + positive count
    const int b = anchor / NANCH;
    float contrib = (q0 && posf) ? conf_loss : 0.0f;
    int pc = (q0 && posf) ? 1 : 0;
    const int bF = __builtin_amdgcn_readfirstlane(b);
    float c0 = (b == bF) ? contrib : 0.0f;
    float c1 = contrib - c0;                    // spillover if wave crosses a row boundary
    for (int off = 32; off; off >>= 1) {
        c0 += __shfl_xor(c0, off);
        c1 += __shfl_xor(c1, off);
        pc += __shfl_xor(pc, off);
    }
    if (lane == 0) {
        if (c0 != 0.f) atomicAdd(&row_pos[bF], c0);
        if (c1 != 0.f) atomicAdd(&row_pos[bF + 1], c1);
        if (pc) atomicAdd(&pos_buckets[(((blockIdx.x << 2) | wid) & 63) * BUCKET_STRIDE], pc);
    }
}

// ---------------- Kernel B: hard-negative mining + conf total ----------------
// grid = 64 rows, block = 1024. Radix-256 select over float bits, 4 rounds.
// Round 0: ballot match-any (values cluster into 1-3 exponent bins -> ~3 loop
// iters, one atomic per distinct bin per wave). Rounds 1-3: plain atomics,
// 4 copies at stride 257 (bank-decorrelated).
__global__ __launch_bounds__(1024) void select_kernel(
    const float* __restrict__ val,
    const int* __restrict__ pos_buckets,
    const float* __restrict__ row_pos,
    float* __restrict__ out)
{
    __shared__ float cl[NANCH];
    __shared__ int hist[4 * HSTRIDE];
    __shared__ int wsum[16];
    __shared__ float fred[16];
    __shared__ int sh_numpos;
    __shared__ unsigned int sh_prefix;
    __shared__ int sh_k, sh_thr;

    const int b = blockIdx.x;
    const int tid = threadIdx.x;
    const int lane = tid & 63, w = tid >> 6;
    const int hofs = (w & 3) * HSTRIDE;
    const float* row = val + b * NANCH;

    if (tid < 64) {
        int v = pos_buckets[tid * BUCKET_STRIDE];
        for (int off = 32; off; off >>= 1) v += __shfl_xor(v, off);
        if (tid == 0) sh_numpos = v;
    }
    for (int i = tid; i < NANCH; i += 1024) cl[i] = row[i];
    __syncthreads();

    int k = 3 * sh_numpos;               // ref: int(3.0 * num_pos), global scalar
    if (k > NANCH - 1) k = NANCH - 1;
    if (k < 0) k = 0;

    unsigned int prefix = 0u;
    for (int r = 0; r < 4; ++r) {
        const int shift = 24 - 8 * r;
        const unsigned int maskHigh = (r == 0) ? 0u : (0xFFFFFFFFu << (shift + 8));
        for (int j = tid; j < 4 * HSTRIDE; j += 1024) hist[j] = 0;
        __syncthreads();
        if (r == 0) {
            // wave-aggregated histogram of the exponent byte
            for (int i0 = 0; i0 < 9216; i0 += 1024) {
                int i = i0 + tid;
                bool valid = (i < NANCH);
                unsigned int u = valid ? __float_as_uint(cl[i]) : 0u;
                int bin = (int)(u >> 24);
                unsigned long long act = __ballot(valid);
                while (act) {
                    int leader = (int)__ffsll((long long)act) - 1;
                    int lbin = __shfl(bin, leader);
                    unsigned long long sm = __ballot(valid && (bin == lbin));
                    if (lane == leader) atomicAdd(&hist[hofs + lbin], (int)__popcll(sm));
                    act &= ~sm;
                }
            }
        } else {
            for (int i = tid; i < NANCH; i += 1024) {
                unsigned int u = __float_as_uint(cl[i]);
                if ((u & maskHigh) == prefix)
                    atomicAdd(&hist[hofs + ((u >> shift) & 0xFF)], 1);
            }
        }
        __syncthreads();
        int h = 0, v = 0;
        if (tid < 256) {
            h = hist[tid] + hist[HSTRIDE + tid] + hist[2 * HSTRIDE + tid]
              + hist[3 * HSTRIDE + tid];
            v = h;
#pragma unroll
            for (int off = 1; off < 64; off <<= 1) {
                int u2 = __shfl_up(v, off);
                if (lane >= off) v += u2;
            }
            if (lane == 63) wsum[w] = v;
        }
        __syncthreads();
        if (tid < 256) {
            int add = 0;
            for (int i = 0; i < w; ++i) add += wsum[i];
            int incl = v + add, excl = incl - h;
            if (excl <= k && k < incl) {
                sh_prefix = prefix | ((unsigned int)tid << shift);
                sh_k = k - excl;
            }
        }
        __syncthreads();
        prefix = sh_prefix;
        k = sh_k;
        __syncthreads();
    }
    const unsigned int T = prefix;

    // stable (index-order) resolution of the k-th equal element
    const int CHUNK = 9;
    int lo = tid * CHUNK; if (lo > NANCH) lo = NANCH;
    int hi = lo + CHUNK; if (hi > NANCH) hi = NANCH;
    int cnt = 0;
    for (int i = lo; i < hi; ++i)
        cnt += (__float_as_uint(cl[i]) == T);
    int v2 = cnt;
#pragma unroll
    for (int off = 1; off < 64; off <<= 1) {
        int u2 = __shfl_up(v2, off);
        if (lane >= off) v2 += u2;
    }
    if (lane == 63) wsum[w] = v2;
    __syncthreads();
    if (tid < 16) {
        int s = wsum[tid];
#pragma unroll
        for (int off = 1; off < 16; off <<= 1) {
            int u2 = __shfl_up(s, off);
            if (lane >= off) s += u2;
        }
        wsum[tid] = s;
    }
    __syncthreads();
    {
        int add = (w == 0) ? 0 : wsum[w - 1];
        int incl = v2 + add, excl = incl - cnt;
        if (excl <= k && k < incl) {
            int need = k - excl, idx = NANCH - 1;
            for (int i = lo; i < hi; ++i) {
                if (__float_as_uint(cl[i]) == T) {
                    if (need == 0) { idx = i; break; }
                    --need;
                }
            }
            sh_thr = idx;
        }
    }
    __syncthreads();

    const float thr = (float)sh_thr;     // quirk: threshold is the argsort INDEX
    float local = 0.f;
    for (int i = tid; i < NANCH; i += 1024) {
        float c = cl[i];
        if (c > thr) local += c;
    }
    for (int off = 32; off; off >>= 1) local += __shfl_xor(local, off);
    if (lane == 0) fred[w] = local;
    __syncthreads();
    if (tid == 0) {
        float t = row_pos[b];
        for (int i = 0; i < 16; ++i) t += fred[i];
        out[b] = t;
    }
}

extern "C" void kernel_launch(void* const* d_in, const int* in_sizes, int n_in,
                              void* d_out, int out_size, void* d_ws, size_t ws_size,
                              hipStream_t stream) {
    const float* pred_conf = (const float*)d_in[0];
    const float* pred_loc  = (const float*)d_in[1];
    const float* gt_conf   = (const float*)d_in[2];
    const float* gt_loc    = (const float*)d_in[3];
    float* out = (float*)d_out;

    int*   pos_buckets = (int*)d_ws;                     // [0, 4096)
    float* row_pos     = (float*)((char*)d_ws + 4096);   // [4096, 4608)
    float* vals        = (float*)((char*)d_ws + 8192);   // [64*8732] floats

    hipMemsetAsync(d_ws, 0, 8192, stream);
    hipMemsetAsync(d_out, 0, 128 * sizeof(float), stream);

    conf_loc_kernel<<<NCONF_BLK + NLOC_BLK, 256, 0, stream>>>(
        pred_conf, gt_conf, pred_loc, gt_loc, vals, pos_buckets, row_pos, out);
    select_kernel<<<NB, 1024, 0, stream>>>(vals, pos_buckets, row_pos, out);
}

// Round 5
// 420.845 us; speedup vs baseline: 1.0216x; 1.0216x over previous
//
#include <hip/hip_runtime.h>
#include <math.h>

#define NCLS 81
#define NANCH 8732
#define NB 64
#define BUCKET_STRIDE 16     // 64 B cacheline spread for int buckets
#define HSTRIDE 257          // bank-decorrelated histogram copy stride (ints)
#define NCONF_BLK 8732       // 64 anchors per block, 16 per wave
#define NLOC_BLK  2240       // 35 chunks * 64 batch rows

// ---------------- Kernel A: conf loss (wave-private DMA, barrier-free) + loc ----------------
// Each WAVE stages its own 16 anchors (1296 floats = 5184 B) into its own LDS
// region via global_load_lds (5 full 1024B chunks + 4-lane 64B tail), scans its
// own gt slice into wave-private labels, then drains ONLY its own vmcnt/lgkmcnt
// with inline asm (compiler cannot see the DMA->LDS->read dependency). No
// __syncthreads anywhere: waves free-run, so a CU keeps ~28 independent waves'
// VMEM in flight instead of convoying at a block barrier.
__global__ __launch_bounds__(256) void conf_loc_kernel(
    const float* __restrict__ pred_conf,
    const float* __restrict__ gt_conf,
    const float* __restrict__ pred_loc,
    const float* __restrict__ gt_loc,
    float* __restrict__ cl_out,       // [B*N] cl_neg (0 for positives)
    int* __restrict__ pos_buckets,    // [64*BUCKET_STRIDE], pre-zeroed
    float* __restrict__ row_pos,      // [128] per-row positive-loss sums, pre-zeroed
    float* __restrict__ out)          // loc part accumulates out[64+b]
{
    __shared__ float sx[5184];        // 4 waves * 1296 floats (20736 B)
    __shared__ int labels[64];        // 4 waves * 16 anchors

    const int tid = threadIdx.x;
    const int lane = tid & 63, w = tid >> 6;

    if (blockIdx.x >= NCONF_BLK) {
        // ---- loc part: smooth-L1-quirk loss, one atomic per wave ----
        const int bid = blockIdx.x - NCONF_BLK;
        const int b = bid & 63;
        const int chunk = bid >> 6;     // 0..34
        const int idx = chunk * 256 + tid;
        float local = 0.f;
        if (idx < NANCH) {
            const float4* p = (const float4*)(pred_loc + (size_t)b * (NANCH * 4));
            const float4* g = (const float4*)(gt_loc + (size_t)b * (NANCH * 4));
            float4 pv = p[idx];
            float4 gv = g[idx];
            float a0 = fabsf(pv.x - gv.x), a1 = fabsf(pv.y - gv.y);
            float a2 = fabsf(pv.z - gv.z), a3 = fabsf(pv.w - gv.w);
            local  = (a0 > 1.f) ? (a0 - 0.5f) : 0.f;
            local += (a1 > 1.f) ? (a1 - 0.5f) : 0.f;
            local += (a2 > 1.f) ? (a2 - 0.5f) : 0.f;
            local += (a3 > 1.f) ? (a3 - 0.5f) : 0.f;
        }
        for (int off = 32; off; off >>= 1) local += __shfl_xor(local, off);
        if (lane == 0 && local != 0.f) atomicAdd(&out[64 + b], local);
        return;
    }

    // ---- conf part ----
    float* sxw = sx + w * 1296;                 // wave-private LDS region (16B-aligned: 5184B steps)
    int* labw = labels + w * 16;
    const size_t gbase = (size_t)blockIdx.x * 5184 + (size_t)w * 1296;  // %4==0 -> 16B-aligned
    const float4* psrc = (const float4*)(pred_conf + gbase);
    const float4* gsrc = (const float4*)(gt_conf + gbase);

    // DMA pred: 324 float4 per wave = 5 full wave-chunks + 4-lane tail
#pragma unroll
    for (int c = 0; c < 5; ++c) {
        const int f4 = c * 64 + lane;
        __builtin_amdgcn_global_load_lds(
            (const __attribute__((address_space(1))) unsigned int*)(psrc + f4),
            (__attribute__((address_space(3))) unsigned int*)(&sxw[f4 * 4]),
            16, 0, 0);
    }
    if (lane < 4) {
        const int f4 = 320 + lane;
        __builtin_amdgcn_global_load_lds(
            (const __attribute__((address_space(1))) unsigned int*)(psrc + f4),
            (__attribute__((address_space(3))) unsigned int*)(&sxw[f4 * 4]),
            16, 0, 0);
    }

    // gt scan (registers) -> wave-private labels; one nonzero per anchor row
    int mycnt = 0;
#pragma unroll
    for (int c = 0; c < 5; ++c) {
        const int f4 = c * 64 + lane;
        float4 g = gsrc[f4];
        float gv[4] = {g.x, g.y, g.z, g.w};
#pragma unroll
        for (int t = 0; t < 4; ++t) {
            if (gv[t] != 0.0f) {
                const int e = 4 * f4 + t;       // < 1296
                const int a = e / 81, cls = e - 81 * a;
                labw[a] = cls;
                mycnt += (cls != 0);
            }
        }
    }
    if (lane < 4) {
        const int f4 = 320 + lane;
        float4 g = gsrc[f4];
        float gv[4] = {g.x, g.y, g.z, g.w};
#pragma unroll
        for (int t = 0; t < 4; ++t) {
            if (gv[t] != 0.0f) {
                const int e = 4 * f4 + t;
                const int a = e / 81, cls = e - 81 * a;
                labw[a] = cls;
                mycnt += (cls != 0);
            }
        }
    }
    for (int off = 32; off; off >>= 1) mycnt += __shfl_xor(mycnt, off);
    if (lane == 0 && mycnt)
        atomicAdd(&pos_buckets[(((blockIdx.x << 2) | w) & 63) * BUCKET_STRIDE], mycnt);

    // drain THIS wave's DMA + label writes (compiler can't see the dependency)
    asm volatile("s_waitcnt vmcnt(0) lgkmcnt(0)" ::: "memory");
    __builtin_amdgcn_sched_barrier(0);

    // softmax consume: 4 lanes per anchor, scalar ds_reads (2-way conflicts = free)
    const int a = lane >> 2, q = lane & 3;
    const float* xr = sxw + a * 81;
    float s0 = 0.f, s1 = 0.f, s2 = 0.f;
#pragma unroll
    for (int j = 0; j < 21; ++j) {
        const int c = q + 4 * j;
        if (c < NCLS) {
            float e = __expf(xr[c]);
            if (j % 3 == 0) s0 += e; else if (j % 3 == 1) s1 += e; else s2 += e;
        }
    }
    float s = s0 + s1 + s2;
    s += __shfl_xor(s, 1);
    s += __shfl_xor(s, 2);
    const float lse = __logf(s);

    const int anchor = blockIdx.x * 64 + w * 16 + a;
    float conf_loss = 0.f;
    bool posf = false;
    if (q == 0) {
        const int lbl = labw[a];
        conf_loss = lse - xr[lbl];              // bit-exact: one-hot dot == x[label]
        posf = (lbl != 0);
        cl_out[anchor] = posf ? 0.0f : conf_loss;
    }

    // per-wave positive-loss row sums (wave spans 16 anchors -> <=1 row boundary)
    const int b = anchor / NANCH;
    const float contrib = posf ? conf_loss : 0.0f;
    const int bF = __builtin_amdgcn_readfirstlane(b);
    float c0 = (b == bF) ? contrib : 0.0f;
    float c1 = contrib - c0;
    for (int off = 32; off; off >>= 1) {
        c0 += __shfl_xor(c0, off);
        c1 += __shfl_xor(c1, off);
    }
    if (lane == 0) {
        if (c0 != 0.f) atomicAdd(&row_pos[bF], c0);
        if (c1 != 0.f) atomicAdd(&row_pos[bF + 1], c1);
    }
}

// ---------------- Kernel B: hard-negative mining + conf total ----------------
// grid = 64 rows, block = 1024. Radix-256 select over float bits, 4 rounds.
// Round 0: ballot match-any (values cluster into 1-3 exponent bins -> ~3 loop
// iters, one atomic per distinct bin per wave). Rounds 1-3: plain atomics,
// 4 copies at stride 257 (bank-decorrelated).
__global__ __launch_bounds__(1024) void select_kernel(
    const float* __restrict__ val,
    const int* __restrict__ pos_buckets,
    const float* __restrict__ row_pos,
    float* __restrict__ out)
{
    __shared__ float cl[NANCH];
    __shared__ int hist[4 * HSTRIDE];
    __shared__ int wsum[16];
    __shared__ float fred[16];
    __shared__ int sh_numpos;
    __shared__ unsigned int sh_prefix;
    __shared__ int sh_k, sh_thr;

    const int b = blockIdx.x;
    const int tid = threadIdx.x;
    const int lane = tid & 63, w = tid >> 6;
    const int hofs = (w & 3) * HSTRIDE;
    const float* row = val + b * NANCH;

    if (tid < 64) {
        int v = pos_buckets[tid * BUCKET_STRIDE];
        for (int off = 32; off; off >>= 1) v += __shfl_xor(v, off);
        if (tid == 0) sh_numpos = v;
    }
    for (int i = tid; i < NANCH; i += 1024) cl[i] = row[i];
    __syncthreads();

    int k = 3 * sh_numpos;               // ref: int(3.0 * num_pos), global scalar
    if (k > NANCH - 1) k = NANCH - 1;
    if (k < 0) k = 0;

    unsigned int prefix = 0u;
    for (int r = 0; r < 4; ++r) {
        const int shift = 24 - 8 * r;
        const unsigned int maskHigh = (r == 0) ? 0u : (0xFFFFFFFFu << (shift + 8));
        for (int j = tid; j < 4 * HSTRIDE; j += 1024) hist[j] = 0;
        __syncthreads();
        if (r == 0) {
            // wave-aggregated histogram of the exponent byte
            for (int i0 = 0; i0 < 9216; i0 += 1024) {
                int i = i0 + tid;
                bool valid = (i < NANCH);
                unsigned int u = valid ? __float_as_uint(cl[i]) : 0u;
                int bin = (int)(u >> 24);
                unsigned long long act = __ballot(valid);
                while (act) {
                    int leader = (int)__ffsll((long long)act) - 1;
                    int lbin = __shfl(bin, leader);
                    unsigned long long sm = __ballot(valid && (bin == lbin));
                    if (lane == leader) atomicAdd(&hist[hofs + lbin], (int)__popcll(sm));
                    act &= ~sm;
                }
            }
        } else {
            for (int i = tid; i < NANCH; i += 1024) {
                unsigned int u = __float_as_uint(cl[i]);
                if ((u & maskHigh) == prefix)
                    atomicAdd(&hist[hofs + ((u >> shift) & 0xFF)], 1);
            }
        }
        __syncthreads();
        int h = 0, v = 0;
        if (tid < 256) {
            h = hist[tid] + hist[HSTRIDE + tid] + hist[2 * HSTRIDE + tid]
              + hist[3 * HSTRIDE + tid];
            v = h;
#pragma unroll
            for (int off = 1; off < 64; off <<= 1) {
                int u2 = __shfl_up(v, off);
                if (lane >= off) v += u2;
            }
            if (lane == 63) wsum[w] = v;
        }
        __syncthreads();
        if (tid < 256) {
            int add = 0;
            for (int i = 0; i < w; ++i) add += wsum[i];
            int incl = v + add, excl = incl - h;
            if (excl <= k && k < incl) {
                sh_prefix = prefix | ((unsigned int)tid << shift);
                sh_k = k - excl;
            }
        }
        __syncthreads();
        prefix = sh_prefix;
        k = sh_k;
        __syncthreads();
    }
    const unsigned int T = prefix;

    // stable (index-order) resolution of the k-th equal element
    const int CHUNK = 9;
    int lo = tid * CHUNK; if (lo > NANCH) lo = NANCH;
    int hi = lo + CHUNK; if (hi > NANCH) hi = NANCH;
    int cnt = 0;
    for (int i = lo; i < hi; ++i)
        cnt += (__float_as_uint(cl[i]) == T);
    int v2 = cnt;
#pragma unroll
    for (int off = 1; off < 64; off <<= 1) {
        int u2 = __shfl_up(v2, off);
        if (lane >= off) v2 += u2;
    }
    if (lane == 63) wsum[w] = v2;
    __syncthreads();
    if (tid < 16) {
        int s = wsum[tid];
#pragma unroll
        for (int off = 1; off < 16; off <<= 1) {
            int u2 = __shfl_up(s, off);
            if (lane >= off) s += u2;
        }
        wsum[tid] = s;
    }
    __syncthreads();
    {
        int add = (w == 0) ? 0 : wsum[w - 1];
        int incl = v2 + add, excl = incl - cnt;
        if (excl <= k && k < incl) {
            int need = k - excl, idx = NANCH - 1;
            for (int i = lo; i < hi; ++i) {
                if (__float_as_uint(cl[i]) == T) {
                    if (need == 0) { idx = i; break; }
                    --need;
                }
            }
            sh_thr = idx;
        }
    }
    __syncthreads();

    const float thr = (float)sh_thr;     // quirk: threshold is the argsort INDEX
    float local = 0.f;
    for (int i = tid; i < NANCH; i += 1024) {
        float c = cl[i];
        if (c > thr) local += c;
    }
    for (int off = 32; off; off >>= 1) local += __shfl_xor(local, off);
    if (lane == 0) fred[w] = local;
    __syncthreads();
    if (tid == 0) {
        float t = row_pos[b];
        for (int i = 0; i < 16; ++i) t += fred[i];
        out[b] = t;
    }
}

extern "C" void kernel_launch(void* const* d_in, const int* in_sizes, int n_in,
                              void* d_out, int out_size, void* d_ws, size_t ws_size,
                              hipStream_t stream) {
    const float* pred_conf = (const float*)d_in[0];
    const float* pred_loc  = (const float*)d_in[1];
    const float* gt_conf   = (const float*)d_in[2];
    const float* gt_loc    = (const float*)d_in[3];
    float* out = (float*)d_out;

    int*   pos_buckets = (int*)d_ws;                     // [0, 4096)
    float* row_pos     = (float*)((char*)d_ws + 4096);   // [4096, 4608)
    float* vals        = (float*)((char*)d_ws + 8192);   // [64*8732] floats

    hipMemsetAsync(d_ws, 0, 8192, stream);
    hipMemsetAsync(d_out, 0, 128 * sizeof(float), stream);

    conf_loc_kernel<<<NCONF_BLK + NLOC_BLK, 256, 0, stream>>>(
        pred_conf, gt_conf, pred_loc, gt_loc, vals, pos_buckets, row_pos, out);
    select_kernel<<<NB, 1024, 0, stream>>>(vals, pos_buckets, row_pos, out);
}

// Round 6
// 393.344 us; speedup vs baseline: 1.0931x; 1.0699x over previous
//
#include <hip/hip_runtime.h>
#include <math.h>

#define NCLS 81
#define NANCH 8732
#define NB 64
#define BUCKET_STRIDE 16     // 64 B cacheline spread for int buckets
#define HSTRIDE 257          // bank-decorrelated histogram copy stride (ints)
#define NLOC_BLK  2240       // 35 chunks * 64 batch rows (run FIRST)
#define NCONF_BLK 1792       // persistent: 7 blocks/CU * 256 CUs
#define NTILES 17464         // 558848 anchors / 32 per tile
#define TILE_A 32            // anchors per tile (8 per wave)
#define WAVE_F 648           // floats per wave per tile (8 anchors * 81)

// ---------------- Kernel A: persistent pipelined conf (wave-private) + loc ----------------
// Each wave loops over tiles (stride NCONF_BLK blocks * 4 waves handled per block
// region). 2-deep pipeline: DMA(t+1) issued BEFORE waiting on tile t via counted
// s_waitcnt vmcnt(3) (in-order vmcnt retirement => everything older than the 3
// newest DMA ops has landed). gt staged to regs one tile ahead. All LDS strictly
// wave-private -> ZERO barriers. Labels: one-hot gt guarantees one nonzero/row.
__global__ __launch_bounds__(256) void conf_loc_kernel(
    const float* __restrict__ pred_conf,
    const float* __restrict__ gt_conf,
    const float* __restrict__ pred_loc,
    const float* __restrict__ gt_loc,
    float* __restrict__ cl_out,       // [B*N] cl_neg (0 for positives)
    int* __restrict__ pos_buckets,    // [64*BUCKET_STRIDE], pre-zeroed
    float* __restrict__ row_pos,      // [128] per-row positive-loss sums, pre-zeroed
    float* __restrict__ locp)         // [2240] loc per-block partials (pure writes)
{
    __shared__ float sx[2][2592];     // double-buffered pred tiles (4 waves * 648)
    __shared__ int labels[2][32];
    __shared__ float red[4];

    const int tid = threadIdx.x;
    const int lane = tid & 63, w = tid >> 6;

    if (blockIdx.x < NLOC_BLK) {
        // ---- loc part: smooth-L1-quirk loss; partial per block (no atomics) ----
        const int bid = blockIdx.x;
        const int b = bid & 63;
        const int chunk = bid >> 6;     // 0..34
        const int idx = chunk * 256 + tid;
        float local = 0.f;
        if (idx < NANCH) {
            const float4* p = (const float4*)(pred_loc + (size_t)b * (NANCH * 4));
            const float4* g = (const float4*)(gt_loc + (size_t)b * (NANCH * 4));
            float4 pv = p[idx];
            float4 gv = g[idx];
            float a0 = fabsf(pv.x - gv.x), a1 = fabsf(pv.y - gv.y);
            float a2 = fabsf(pv.z - gv.z), a3 = fabsf(pv.w - gv.w);
            local  = (a0 > 1.f) ? (a0 - 0.5f) : 0.f;
            local += (a1 > 1.f) ? (a1 - 0.5f) : 0.f;
            local += (a2 > 1.f) ? (a2 - 0.5f) : 0.f;
            local += (a3 > 1.f) ? (a3 - 0.5f) : 0.f;
        }
        for (int off = 32; off; off >>= 1) local += __shfl_xor(local, off);
        if (lane == 0) red[w] = local;
        __syncthreads();
        if (tid == 0) locp[bid] = red[0] + red[1] + red[2] + red[3];
        return;
    }

    // ---- conf part: persistent, pipelined ----
    const int pid = blockIdx.x - NLOC_BLK;        // 0..1791
    float* swA = &sx[0][w * WAVE_F];              // wave-private LDS slices
    float* swB = &sx[1][w * WAVE_F];
    int pacc = 0;                                 // positives, accumulated over tiles

#define DMA3(dst, src)                                                              \
    do {                                                                            \
        __builtin_amdgcn_global_load_lds(                                           \
            (const __attribute__((address_space(1))) unsigned int*)((src) + lane),  \
            (__attribute__((address_space(3))) unsigned int*)(&(dst)[lane * 4]),    \
            16, 0, 0);                                                              \
        __builtin_amdgcn_global_load_lds(                                           \
            (const __attribute__((address_space(1))) unsigned int*)((src) + 64 + lane), \
            (__attribute__((address_space(3))) unsigned int*)(&(dst)[(64 + lane) * 4]), \
            16, 0, 0);                                                              \
        if (lane < 34)                                                              \
            __builtin_amdgcn_global_load_lds(                                       \
                (const __attribute__((address_space(1))) unsigned int*)((src) + 128 + lane), \
                (__attribute__((address_space(3))) unsigned int*)(&(dst)[(128 + lane) * 4]), \
                16, 0, 0);                                                          \
    } while (0)

    int T = pid;
    {
        const float4* ps = (const float4*)(pred_conf + (size_t)T * 2592 + w * WAVE_F);
        DMA3(swA, ps);
    }
    const float4* gs = (const float4*)(gt_conf + (size_t)T * 2592 + w * WAVE_F);
    float4 g0 = gs[lane];
    float4 g1 = gs[64 + lane];
    float4 g2 = (lane < 34) ? gs[128 + lane] : float4{0.f, 0.f, 0.f, 0.f};

    int cur = 0;
    for (;;) {
        const int Tn = T + NCONF_BLK;
        const bool hasN = (Tn < NTILES);
        float* swc = cur ? swB : swA;
        float* swn = cur ? swA : swB;

        if (hasN) {
            const float4* ps = (const float4*)(pred_conf + (size_t)Tn * 2592 + w * WAVE_F);
            DMA3(swn, ps);
            asm volatile("s_waitcnt vmcnt(3)" ::: "memory");   // retire tile T's DMA+gt
        } else {
            asm volatile("s_waitcnt vmcnt(0)" ::: "memory");
        }
        __builtin_amdgcn_sched_barrier(0);

        // process gt regs (tile T) -> wave-private labels
        {
            const float4 gg[3] = {g0, g1, g2};
#pragma unroll
            for (int c = 0; c < 3; ++c) {
                const int f4 = c * 64 + lane;
                float gv[4] = {gg[c].x, gg[c].y, gg[c].z, gg[c].w};
#pragma unroll
                for (int t = 0; t < 4; ++t) {
                    if (gv[t] != 0.0f) {
                        const int e = 4 * f4 + t;            // < 648
                        const int a = e / 81, cls = e - 81 * a;
                        labels[cur][w * 8 + a] = cls;
                        pacc += (cls != 0);
                    }
                }
            }
        }
        if (hasN) {                                           // stage next gt (overwrites after use)
            const float4* gn = (const float4*)(gt_conf + (size_t)Tn * 2592 + w * WAVE_F);
            g0 = gn[lane];
            g1 = gn[64 + lane];
            g2 = (lane < 34) ? gn[128 + lane] : float4{0.f, 0.f, 0.f, 0.f};
        }
        asm volatile("s_waitcnt lgkmcnt(0)" ::: "memory");    // label ds_writes visible to self
        __builtin_amdgcn_sched_barrier(0);

        // consume tile T: 8 lanes per anchor
        {
            const int a = lane >> 3, r = lane & 7;
            const float* xr = swc + a * 81;
            float s = 0.f;
#pragma unroll
            for (int j = 0; j < 10; ++j) s += __expf(xr[r + 8 * j]);   // c = r+8j <= 79
            if (r == 0) s += __expf(xr[80]);
            s += __shfl_xor(s, 1);
            s += __shfl_xor(s, 2);
            s += __shfl_xor(s, 4);
            const float lse = __logf(s);

            const int anchor = T * TILE_A + w * 8 + a;
            float contrib = 0.f;
            if (r == 0) {
                const int lbl = labels[cur][w * 8 + a];
                const float cl = lse - xr[lbl];               // one-hot dot == x[label]
                const bool posf = (lbl != 0);
                cl_out[anchor] = posf ? 0.0f : cl;
                if (posf) contrib = cl;
            }
            const int b = anchor / NANCH;
            const int bF = __builtin_amdgcn_readfirstlane(b);
            float c0 = (b == bF) ? contrib : 0.0f;
            float c1 = contrib - c0;                          // row-boundary spillover
            for (int off = 32; off; off >>= 1) {
                c0 += __shfl_xor(c0, off);
                c1 += __shfl_xor(c1, off);
            }
            if (lane == 0) {
                if (c0 != 0.f) atomicAdd(&row_pos[bF], c0);
                if (c1 != 0.f) atomicAdd(&row_pos[bF + 1], c1);
            }
        }

        if (!hasN) break;
        T = Tn;
        cur ^= 1;
    }
#undef DMA3

    // one pos-count atomic per wave for the whole kernel
    for (int off = 32; off; off >>= 1) pacc += __shfl_xor(pacc, off);
    if (lane == 0 && pacc)
        atomicAdd(&pos_buckets[(((pid << 2) | w) & 63) * BUCKET_STRIDE], pacc);
}

// ---------------- Kernel B: hard-negative mining + conf total + loc total ----------------
// grid = 64 rows, block = 1024. Radix-256 select over float bits, 4 rounds.
__global__ __launch_bounds__(1024) void select_kernel(
    const float* __restrict__ val,
    const int* __restrict__ pos_buckets,
    const float* __restrict__ row_pos,
    const float* __restrict__ locp,
    float* __restrict__ out)
{
    __shared__ float cl[NANCH];
    __shared__ int hist[4 * HSTRIDE];
    __shared__ int wsum[16];
    __shared__ float fred[16];
    __shared__ int sh_numpos;
    __shared__ unsigned int sh_prefix;
    __shared__ int sh_k, sh_thr;

    const int b = blockIdx.x;
    const int tid = threadIdx.x;
    const int lane = tid & 63, w = tid >> 6;
    const int hofs = (w & 3) * HSTRIDE;
    const float* row = val + b * NANCH;

    if (tid < 64) {
        int v = pos_buckets[tid * BUCKET_STRIDE];
        for (int off = 32; off; off >>= 1) v += __shfl_xor(v, off);
        if (tid == 0) sh_numpos = v;
    } else if (tid < 128) {
        // loc total: sum 35 chunk partials for row b (wave 1, independent)
        float v = (lane < 35) ? locp[lane * 64 + b] : 0.f;
        for (int off = 32; off; off >>= 1) v += __shfl_xor(v, off);
        if (lane == 0) out[64 + b] = v;
    }
    for (int i = tid; i < NANCH; i += 1024) cl[i] = row[i];
    __syncthreads();

    int k = 3 * sh_numpos;               // ref: int(3.0 * num_pos), global scalar
    if (k > NANCH - 1) k = NANCH - 1;
    if (k < 0) k = 0;

    unsigned int prefix = 0u;
    for (int r = 0; r < 4; ++r) {
        const int shift = 24 - 8 * r;
        const unsigned int maskHigh = (r == 0) ? 0u : (0xFFFFFFFFu << (shift + 8));
        for (int j = tid; j < 4 * HSTRIDE; j += 1024) hist[j] = 0;
        __syncthreads();
        if (r == 0) {
            // wave-aggregated histogram of the exponent byte
            for (int i0 = 0; i0 < 9216; i0 += 1024) {
                int i = i0 + tid;
                bool valid = (i < NANCH);
                unsigned int u = valid ? __float_as_uint(cl[i]) : 0u;
                int bin = (int)(u >> 24);
                unsigned long long act = __ballot(valid);
                while (act) {
                    int leader = (int)__ffsll((long long)act) - 1;
                    int lbin = __shfl(bin, leader);
                    unsigned long long sm = __ballot(valid && (bin == lbin));
                    if (lane == leader) atomicAdd(&hist[hofs + lbin], (int)__popcll(sm));
                    act &= ~sm;
                }
            }
        } else {
            for (int i = tid; i < NANCH; i += 1024) {
                unsigned int u = __float_as_uint(cl[i]);
                if ((u & maskHigh) == prefix)
                    atomicAdd(&hist[hofs + ((u >> shift) & 0xFF)], 1);
            }
        }
        __syncthreads();
        int h = 0, v = 0;
        if (tid < 256) {
            h = hist[tid] + hist[HSTRIDE + tid] + hist[2 * HSTRIDE + tid]
              + hist[3 * HSTRIDE + tid];
            v = h;
#pragma unroll
            for (int off = 1; off < 64; off <<= 1) {
                int u2 = __shfl_up(v, off);
                if (lane >= off) v += u2;
            }
            if (lane == 63) wsum[w] = v;
        }
        __syncthreads();
        if (tid < 256) {
            int add = 0;
            for (int i = 0; i < w; ++i) add += wsum[i];
            int incl = v + add, excl = incl - h;
            if (excl <= k && k < incl) {
                sh_prefix = prefix | ((unsigned int)tid << shift);
                sh_k = k - excl;
            }
        }
        __syncthreads();
        prefix = sh_prefix;
        k = sh_k;
        __syncthreads();
    }
    const unsigned int T = prefix;

    // stable (index-order) resolution of the k-th equal element
    const int CHUNK = 9;
    int lo = tid * CHUNK; if (lo > NANCH) lo = NANCH;
    int hi = lo + CHUNK; if (hi > NANCH) hi = NANCH;
    int cnt = 0;
    for (int i = lo; i < hi; ++i)
        cnt += (__float_as_uint(cl[i]) == T);
    int v2 = cnt;
#pragma unroll
    for (int off = 1; off < 64; off <<= 1) {
        int u2 = __shfl_up(v2, off);
        if (lane >= off) v2 += u2;
    }
    if (lane == 63) wsum[w] = v2;
    __syncthreads();
    if (tid < 16) {
        int s = wsum[tid];
#pragma unroll
        for (int off = 1; off < 16; off <<= 1) {
            int u2 = __shfl_up(s, off);
            if (lane >= off) s += u2;
        }
        wsum[tid] = s;
    }
    __syncthreads();
    {
        int add = (w == 0) ? 0 : wsum[w - 1];
        int incl = v2 + add, excl = incl - cnt;
        if (excl <= k && k < incl) {
            int need = k - excl, idx = NANCH - 1;
            for (int i = lo; i < hi; ++i) {
                if (__float_as_uint(cl[i]) == T) {
                    if (need == 0) { idx = i; break; }
                    --need;
                }
            }
            sh_thr = idx;
        }
    }
    __syncthreads();

    const float thr = (float)sh_thr;     // quirk: threshold is the argsort INDEX
    float local = 0.f;
    for (int i = tid; i < NANCH; i += 1024) {
        float c = cl[i];
        if (c > thr) local += c;
    }
    for (int off = 32; off; off >>= 1) local += __shfl_xor(local, off);
    if (lane == 0) fred[w] = local;
    __syncthreads();
    if (tid == 0) {
        float t = row_pos[b];
        for (int i = 0; i < 16; ++i) t += fred[i];
        out[b] = t;
    }
}

extern "C" void kernel_launch(void* const* d_in, const int* in_sizes, int n_in,
                              void* d_out, int out_size, void* d_ws, size_t ws_size,
                              hipStream_t stream) {
    const float* pred_conf = (const float*)d_in[0];
    const float* pred_loc  = (const float*)d_in[1];
    const float* gt_conf   = (const float*)d_in[2];
    const float* gt_loc    = (const float*)d_in[3];
    float* out = (float*)d_out;

    int*   pos_buckets = (int*)d_ws;                     // [0, 4096)
    float* row_pos     = (float*)((char*)d_ws + 4096);   // [4096, 4608)
    float* locp        = (float*)((char*)d_ws + 5120);   // [5120, 14080): 2240 floats
    float* vals        = (float*)((char*)d_ws + 16384);  // [64*8732] floats

    hipMemsetAsync(d_ws, 0, 8192, stream);               // pos_buckets + row_pos

    conf_loc_kernel<<<NLOC_BLK + NCONF_BLK, 256, 0, stream>>>(
        pred_conf, gt_conf, pred_loc, gt_loc, vals, pos_buckets, row_pos, locp);
    select_kernel<<<NB, 1024, 0, stream>>>(vals, pos_buckets, row_pos, locp, out);
}